// Round 4
// baseline (482.336 us; speedup 1.0000x reference)
//
#include <hip/hip_runtime.h>
#include <math.h>

typedef __attribute__((ext_vector_type(8))) short short8;
typedef __attribute__((ext_vector_type(4))) float f32x4;
typedef unsigned short ushort_t;

__device__ inline unsigned short f2bf_rn(float f) {
    unsigned u = __builtin_bit_cast(unsigned, f);
    u += 0x7FFF + ((u >> 16) & 1);
    return (unsigned short)(u >> 16);
}
__device__ inline float bf2f(unsigned short h) {
    unsigned u = ((unsigned)h) << 16;
    return __builtin_bit_cast(float, u);
}

// ---------------------------------------------------------------------------
// Pure-bf16 NT GEMM over virtual K' = 3*KSEG (Ah*Bh + Ah*Bl + Al*Bh, one fp32
// accumulator). 128x128 tile, BK=64, 4 waves. Reg-staged prefetch, raw
// s_barrier + lgkmcnt(0). LDS XOR swizzle slot^(row&7). NSPLIT over blockIdx.z.
// (unchanged from round 3 — verified)
// ---------------------------------------------------------------------------
#define ISSUE(ST, RA, RB)                                                      \
  do {                                                                         \
    int s_ = (ST);                                                             \
    int sg_ = s_ / SPS;                                                        \
    int k0_ = (s_ - sg_ * SPS) * 64;                                           \
    const unsigned short* Ap_ = (sg_ < 2) ? Ah : Al;                           \
    const unsigned short* Bp_ = (sg_ == 1) ? Bl : Bh;                          \
    _Pragma("unroll") for (int i_ = 0; i_ < 4; ++i_) {                         \
      RA[i_] = *(const uint4*)(Ap_ + (size_t)(bm + crow[i_]) * lda + k0_ + csl[i_] * 8); \
      RB[i_] = *(const uint4*)(Bp_ + (size_t)(bn + crow[i_]) * ldb + k0_ + csl[i_] * 8); \
    }                                                                          \
  } while (0)

#define PHASE(IT, RWa, RWb, RLa, RLb)                                          \
  do {                                                                         \
    _Pragma("unroll") for (int i_ = 0; i_ < 4; ++i_) {                         \
      int wsl_ = csl[i_] ^ (crow[i_] & 7);                                     \
      *(uint4*)&As[crow[i_]][wsl_ * 8] = RWa[i_];                              \
      *(uint4*)&Bs[crow[i_]][wsl_ * 8] = RWb[i_];                              \
    }                                                                          \
    if ((IT) + 1 < CHUNK) { ISSUE(st0 + (IT) + 1, RLa, RLb); }                 \
    asm volatile("s_waitcnt lgkmcnt(0)\n\ts_barrier" ::: "memory");            \
    _Pragma("unroll") for (int kk = 0; kk < 2; ++kk) {                         \
      short8 af[4], bf[4];                                                     \
      _Pragma("unroll") for (int f = 0; f < 4; ++f) {                          \
        int ar = wm * 64 + f * 16 + r15;                                       \
        int as_ = (kk * 4 + ksl) ^ (ar & 7);                                   \
        af[f] = *(const short8*)&As[ar][as_ * 8];                              \
        int br = wn * 64 + f * 16 + r15;                                       \
        int bs_ = (kk * 4 + ksl) ^ (br & 7);                                   \
        bf[f] = *(const short8*)&Bs[br][bs_ * 8];                              \
      }                                                                        \
      _Pragma("unroll") for (int i_ = 0; i_ < 4; ++i_)                         \
        _Pragma("unroll") for (int j_ = 0; j_ < 4; ++j_)                       \
          acc[i_][j_] = __builtin_amdgcn_mfma_f32_16x16x32_bf16(               \
              af[i_], bf[j_], acc[i_][j_], 0, 0, 0);                           \
    }                                                                          \
    asm volatile("s_barrier" ::: "memory");                                    \
  } while (0)

template <int KSEG, int NSPLIT>
__global__ __launch_bounds__(256, 2) void gemm_bf16(
    const unsigned short* __restrict__ Ah, const unsigned short* __restrict__ Al, int lda,
    const unsigned short* __restrict__ Bh, const unsigned short* __restrict__ Bl, int ldb,
    float* __restrict__ Cout, int ldc)
{
    constexpr int SPS = KSEG / 64;
    constexpr int NST = 3 * SPS;
    constexpr int CHUNK = NST / NSPLIT;

    __shared__ __align__(16) unsigned short As[128][64];
    __shared__ __align__(16) unsigned short Bs[128][64];

    const int tid = threadIdx.x, lane = tid & 63, w = tid >> 6;
    const int wm = w >> 1, wn = w & 1;
    const int bm = blockIdx.y * 128, bn = blockIdx.x * 128;
    const int st0 = blockIdx.z * CHUNK;
    const int r15 = lane & 15, ksl = lane >> 4;

    int crow[4], csl[4];
#pragma unroll
    for (int i = 0; i < 4; ++i) { int c = tid + i * 256; crow[i] = c >> 3; csl[i] = c & 7; }

    f32x4 acc[4][4];
#pragma unroll
    for (int i = 0; i < 4; ++i)
#pragma unroll
        for (int j = 0; j < 4; ++j) acc[i][j] = (f32x4){0.f, 0.f, 0.f, 0.f};

    uint4 rA0[4], rB0[4], rA1[4], rB1[4];
    ISSUE(st0, rA0, rB0);

#pragma unroll 1
    for (int it = 0; it < CHUNK; it += 2) {
        PHASE(it,     rA0, rB0, rA1, rB1);
        PHASE(it + 1, rA1, rB1, rA0, rB0);
    }

    float* Cz = Cout + (size_t)blockIdx.z * (size_t)(gridDim.y * 128) * ldc;
#pragma unroll
    for (int i = 0; i < 4; ++i) {
        int rowb = bm + wm * 64 + i * 16 + (lane >> 4) * 4;
#pragma unroll
        for (int j = 0; j < 4; ++j) {
            int colb = bn + wn * 64 + j * 16 + r15;
#pragma unroll
            for (int r = 0; r < 4; ++r)
                Cz[(size_t)(rowb + r) * ldc + colb] = acc[i][j][r];
        }
    }
}

// ---------------------------------------------------------------------------
// Reduce NS partials + bias, write C fp32 and hi/lo bf16. (unchanged)
// ---------------------------------------------------------------------------
template <int NS, bool BIAS>
__global__ __launch_bounds__(256) void reduce_kernel(
    const float* __restrict__ part, size_t pstride4,
    const float* __restrict__ bias, float* __restrict__ C,
    unsigned short* __restrict__ Ch, unsigned short* __restrict__ Cl, int N)
{
    size_t idx = (size_t)blockIdx.x * 256 + threadIdx.x;
    const float4* p = (const float4*)part;
    float4 s = p[idx];
#pragma unroll
    for (int z = 1; z < NS; ++z) {
        float4 t = p[idx + (size_t)z * pstride4];
        s.x += t.x; s.y += t.y; s.z += t.z; s.w += t.w;
    }
    if (BIAS) {
        int col = (int)((idx * 4) & (size_t)(N - 1));
        s.x += bias[col]; s.y += bias[col + 1]; s.z += bias[col + 2]; s.w += bias[col + 3];
    }
    ((float4*)C)[idx] = s;
    float v[4] = {s.x, s.y, s.z, s.w};
    unsigned short h[4], l[4];
#pragma unroll
    for (int q = 0; q < 4; ++q) { h[q] = f2bf_rn(v[q]); l[q] = f2bf_rn(v[q] - bf2f(h[q])); }
    uint2 hp = make_uint2((unsigned)h[0] | ((unsigned)h[1] << 16), (unsigned)h[2] | ((unsigned)h[3] << 16));
    uint2 lp = make_uint2((unsigned)l[0] | ((unsigned)l[1] << 16), (unsigned)l[2] | ((unsigned)l[3] << 16));
    ((uint2*)Ch)[idx] = hp;
    ((uint2*)Cl)[idx] = lp;
}

// ---------------------------------------------------------------------------
// Flash attention, split-bf16, online softmax with defer-max (thr=8).
// grid (z=8 kv-splits, 32 q-tiles); 256 thr = 4 waves x 16 q-rows.
// Q in regs; K staged in swizzled LDS; V B-frags direct from global
// (wave w owns d-chunk w*128..+128, no redundancy); P via swizzled LDS.
// Outputs per-z partials Opart[z][2048][512] fp32 + Mpart/Lpart[z][2048].
// ---------------------------------------------------------------------------
#define SLK(r, s) ((s) ^ (((s) >> 3) & 3) ^ ((((r) ^ ((r) >> 3))) & 7))

__global__ __launch_bounds__(256, 2) void flash_attn(
    const unsigned short* __restrict__ Qh, const unsigned short* __restrict__ Ql,
    const unsigned short* __restrict__ Kh, const unsigned short* __restrict__ Kl,
    int ldqk,
    const unsigned short* __restrict__ VTh, const unsigned short* __restrict__ VTl,
    float* __restrict__ Opart, float* __restrict__ Mpart, float* __restrict__ Lpart)
{
    const int tid = threadIdx.x, lane = tid & 63, w = tid >> 6;
    const int z = blockIdx.x;          // kv split (XCD-affine: innermost grid dim)
    const int q0 = blockIdx.y * 64;
    const int s0 = z * 256;
    const int cc = lane & 15, g = lane >> 4;

    __shared__ __align__(16) unsigned short KsH[32][256], KsL[32][256];
    __shared__ __align__(16) unsigned short PsH[64][32], PsL[64][32];
    __shared__ float Fs[64];
    __shared__ int flagAny[4];

    // Q fragments (wave's 16 q-rows, hi+lo) — A-frag: row=lane&15, k=g*8..
    short8 qh[8], qlv[8];
#pragma unroll
    for (int ks = 0; ks < 8; ++ks) {
        const size_t qoff = (size_t)(q0 + w * 16 + cc) * ldqk + ks * 32 + g * 8;
        qh[ks]  = *(const short8*)(Qh + qoff);
        qlv[ks] = *(const short8*)(Ql + qoff);
    }

    f32x4 acc[4][8];
#pragma unroll
    for (int a = 0; a < 4; ++a)
#pragma unroll
        for (int b = 0; b < 8; ++b) acc[a][b] = (f32x4){0.f, 0.f, 0.f, 0.f};
    float m[4] = {-1e30f, -1e30f, -1e30f, -1e30f};
    float l[4] = {0.f, 0.f, 0.f, 0.f};

#pragma unroll 1
    for (int sub = 0; sub < 8; ++sub) {
        __syncthreads();   // previous subtile's Ks/Ps/Fs reads done
        // ---- stage K subtile (32 kv x 256 k, hi+lo) into swizzled LDS ----
#pragma unroll
        for (int i = 0; i < 4; ++i) {
            int idx = tid + i * 256;                 // 0..1023
            int row = (idx >> 3) & 31;
            int sl  = (idx & 7) | ((idx >> 8) << 3); // 16B slot 0..31
            size_t go = (size_t)(s0 + sub * 32 + row) * ldqk + sl * 8;
            uint4 vh = *(const uint4*)(Kh + go);
            uint4 vl = *(const uint4*)(Kl + go);
            int sw = SLK(row, sl);
            *(uint4*)&KsH[row][sw * 8] = vh;
            *(uint4*)&KsL[row][sw * 8] = vl;
        }
        __syncthreads();

        // ---- QK^T: S[16 q][32 kv], 3-pass split ----
        f32x4 sac[2];
        sac[0] = (f32x4){0.f, 0.f, 0.f, 0.f};
        sac[1] = (f32x4){0.f, 0.f, 0.f, 0.f};
#pragma unroll
        for (int ks = 0; ks < 8; ++ks) {
#pragma unroll
            for (int t = 0; t < 2; ++t) {
                int row = t * 16 + cc;
                int sw = SLK(row, ks * 4 + g);
                short8 bh = *(const short8*)&KsH[row][sw * 8];
                short8 bl = *(const short8*)&KsL[row][sw * 8];
                sac[t] = __builtin_amdgcn_mfma_f32_16x16x32_bf16(qh[ks], bh, sac[t], 0, 0, 0);
                sac[t] = __builtin_amdgcn_mfma_f32_16x16x32_bf16(qh[ks], bl, sac[t], 0, 0, 0);
                sac[t] = __builtin_amdgcn_mfma_f32_16x16x32_bf16(qlv[ks], bh, sac[t], 0, 0, 0);
            }
        }

        // ---- online softmax (rows r -> q = w*16 + g*4 + r) ----
        float mt[4], fr[4];
        bool nb = false;
#pragma unroll
        for (int r = 0; r < 4; ++r) {
            float v = fmaxf(sac[0][r], sac[1][r]);
#pragma unroll
            for (int o = 8; o >= 1; o >>= 1) v = fmaxf(v, __shfl_xor(v, o));
            mt[r] = v;
            nb = nb || (v > m[r] + 8.f);
        }
        const int need = __any((int)nb);
        if (need) {
#pragma unroll
            for (int r = 0; r < 4; ++r) {
                float mn = fmaxf(m[r], mt[r]);
                fr[r] = __expf(m[r] - mn);
                m[r] = mn;
                l[r] *= fr[r];
            }
        } else {
#pragma unroll
            for (int r = 0; r < 4; ++r) fr[r] = 1.f;
        }
        if (cc == 0) {
#pragma unroll
            for (int r = 0; r < 4; ++r) Fs[w * 16 + g * 4 + r] = fr[r];
        }
        if (lane == 0) flagAny[w] = need;

        // ---- P = exp(S - m): accumulate l, hi/lo to swizzled LDS ----
#pragma unroll
        for (int t = 0; t < 2; ++t) {
            float ps[4];
#pragma unroll
            for (int r = 0; r < 4; ++r) {
                float p = __expf(sac[t][r] - m[r]);
                ps[r] = p;
                unsigned short ph = f2bf_rn(p);
                unsigned short pl = f2bf_rn(p - bf2f(ph));
                int qq = w * 16 + g * 4 + r;
                int kv = cc + 16 * t;
                int col = (((kv >> 3) ^ (qq & 3)) << 3) | (kv & 7);
                PsH[qq][col] = ph;
                PsL[qq][col] = pl;
            }
#pragma unroll
            for (int r = 0; r < 4; ++r) {
                float s = ps[r];
#pragma unroll
                for (int o = 8; o >= 1; o >>= 1) s += __shfl_xor(s, o);
                l[r] += s;
            }
        }
        __syncthreads();   // P, Fs, flags visible block-wide

        // ---- rescale acc (all 64 q rows) if any wave's max moved ----
        int anyf = flagAny[0] | flagAny[1] | flagAny[2] | flagAny[3];
        if (anyf) {
#pragma unroll
            for (int qt = 0; qt < 4; ++qt)
#pragma unroll
                for (int r = 0; r < 4; ++r) {
                    float fq = Fs[qt * 16 + g * 4 + r];
#pragma unroll
                    for (int dt = 0; dt < 8; ++dt) acc[qt][dt][r] *= fq;
                }
        }

        // ---- PV: acc[qt][dt] += P * V  (V B-frags direct from global) ----
        short8 pah[4], pal[4];
#pragma unroll
        for (int qt = 0; qt < 4; ++qt) {
            int qr = qt * 16 + cc;
            int col = (g ^ (qr & 3)) << 3;
            pah[qt] = *(const short8*)&PsH[qr][col];
            pal[qt] = *(const short8*)&PsL[qr][col];
        }
#pragma unroll
        for (int dt = 0; dt < 8; ++dt) {
            size_t vo = (size_t)(w * 128 + dt * 16 + cc) * 2048 + s0 + sub * 32 + g * 8;
            short8 vh = *(const short8*)(VTh + vo);
            short8 vl = *(const short8*)(VTl + vo);
#pragma unroll
            for (int qt = 0; qt < 4; ++qt) {
                acc[qt][dt] = __builtin_amdgcn_mfma_f32_16x16x32_bf16(pah[qt], vh, acc[qt][dt], 0, 0, 0);
                acc[qt][dt] = __builtin_amdgcn_mfma_f32_16x16x32_bf16(pah[qt], vl, acc[qt][dt], 0, 0, 0);
                acc[qt][dt] = __builtin_amdgcn_mfma_f32_16x16x32_bf16(pal[qt], vh, acc[qt][dt], 0, 0, 0);
            }
        }
    }

    // ---- epilogue: partial O + softmax stats ----
#pragma unroll
    for (int qt = 0; qt < 4; ++qt)
#pragma unroll
        for (int dt = 0; dt < 8; ++dt)
#pragma unroll
            for (int r = 0; r < 4; ++r) {
                int row = q0 + qt * 16 + g * 4 + r;
                int col = w * 128 + dt * 16 + cc;
                Opart[((size_t)z * 2048 + row) * 512 + col] = acc[qt][dt][r];
            }
    if (cc == 0) {
#pragma unroll
        for (int r = 0; r < 4; ++r) {
            int row = q0 + w * 16 + g * 4 + r;
            Mpart[z * 2048 + row] = m[r];
            Lpart[z * 2048 + row] = l[r];
        }
    }
}

// ---------------------------------------------------------------------------
// Combine 8 kv-split partials -> O row, write hi/lo bf16. One block per q-row.
// ---------------------------------------------------------------------------
__global__ __launch_bounds__(256) void flash_combine(
    const float* __restrict__ Opart, const float* __restrict__ Mpart,
    const float* __restrict__ Lpart,
    unsigned short* __restrict__ Oh, unsigned short* __restrict__ Ol)
{
    const int q = blockIdx.x;
    const int tid = threadIdx.x;
    float wz[8];
    float mstar = -1e30f;
#pragma unroll
    for (int zz = 0; zz < 8; ++zz) { wz[zz] = Mpart[zz * 2048 + q]; mstar = fmaxf(mstar, wz[zz]); }
    float L = 0.f;
#pragma unroll
    for (int zz = 0; zz < 8; ++zz) {
        float e = __expf(wz[zz] - mstar);
        L += e * Lpart[zz * 2048 + q];
        wz[zz] = e;
    }
    float invL = 1.f / L;
    int d = tid * 2;
    float sx = 0.f, sy = 0.f;
#pragma unroll
    for (int zz = 0; zz < 8; ++zz) {
        const float2 t = *(const float2*)(Opart + ((size_t)zz * 2048 + q) * 512 + d);
        sx += wz[zz] * t.x;
        sy += wz[zz] * t.y;
    }
    sx *= invL; sy *= invL;
    unsigned short h0 = f2bf_rn(sx), h1 = f2bf_rn(sy);
    unsigned short l0 = f2bf_rn(sx - bf2f(h0)), l1 = f2bf_rn(sy - bf2f(h1));
    *(unsigned*)(Oh + (size_t)q * 512 + d) = (unsigned)h0 | ((unsigned)h1 << 16);
    *(unsigned*)(Ol + (size_t)q * 512 + d) = (unsigned)l0 | ((unsigned)l1 << 16);
}

// ---------------------------------------------------------------------------
// Row L2 normalize in place (fp32). (unchanged)
// ---------------------------------------------------------------------------
__global__ __launch_bounds__(256) void l2norm_kernel(float* __restrict__ V, int ld,
                                                     int coloff, int D)
{
    __shared__ float red[8];
    const int tid = threadIdx.x;
    float* p = V + (size_t)blockIdx.x * ld + coloff;
    float s = 0.f;
    for (int i = tid; i < D; i += 256) { float v = p[i]; s = fmaf(v, v, s); }
#pragma unroll
    for (int o = 32; o; o >>= 1) s += __shfl_down(s, o);
    if ((tid & 63) == 0) red[tid >> 6] = s;
    __syncthreads();
    float scale = 1.f / sqrtf(red[0] + red[1] + red[2] + red[3]);
    for (int i = tid; i < D; i += 256) p[i] *= scale;
}

// ---------------------------------------------------------------------------
// Transpose-convert fp32 -> hi/lo bf16 transposed. (unchanged)
// ---------------------------------------------------------------------------
__global__ __launch_bounds__(256) void tc_kernel(
    const float* __restrict__ in, int ldin,
    unsigned short* __restrict__ oh, unsigned short* __restrict__ ol,
    int ldo, int rowoff)
{
    __shared__ float tile[32][33];
    int bx = blockIdx.x * 32, by = blockIdx.y * 32;
    int tx = threadIdx.x & 31, ty = threadIdx.x >> 5;
#pragma unroll
    for (int i = 0; i < 32; i += 8)
        tile[ty + i][tx] = in[(size_t)(by + ty + i) * ldin + bx + tx];
    __syncthreads();
#pragma unroll
    for (int i = 0; i < 32; i += 8) {
        float v = tile[tx][ty + i];
        unsigned short h = f2bf_rn(v);
        unsigned short l = f2bf_rn(v - bf2f(h));
        size_t o = (size_t)(rowoff + bx + ty + i) * ldo + by + tx;
        oh[o] = h; ol[o] = l;
    }
}

// ---------------------------------------------------------------------------
// Elementwise fp32 -> hi/lo bf16. (unchanged)
// ---------------------------------------------------------------------------
__global__ __launch_bounds__(256) void convert_hl(
    const float* __restrict__ in, unsigned short* __restrict__ oh,
    unsigned short* __restrict__ ol)
{
    size_t idx = (size_t)blockIdx.x * 256 + threadIdx.x;
    float4 s = ((const float4*)in)[idx];
    float v[4] = {s.x, s.y, s.z, s.w};
    unsigned short h[4], l[4];
#pragma unroll
    for (int q = 0; q < 4; ++q) { h[q] = f2bf_rn(v[q]); l[q] = f2bf_rn(v[q] - bf2f(h[q])); }
    uint2 hp = make_uint2((unsigned)h[0] | ((unsigned)h[1] << 16), (unsigned)h[2] | ((unsigned)h[3] << 16));
    uint2 lp = make_uint2((unsigned)l[0] | ((unsigned)l[1] << 16), (unsigned)l[2] | ((unsigned)l[3] << 16));
    ((uint2*)oh)[idx] = hp;
    ((uint2*)ol)[idx] = lp;
}

__global__ __launch_bounds__(256) void concat_bias(
    const float* bk1, const float* bq1, const float* bk2, const float* bq2,
    const float* bv2, float* b1, float* b2)
{
    int i = blockIdx.x * 256 + threadIdx.x;
    if (i < 512) b1[i] = (i < 256) ? bk1[i] : bq1[i - 256];
    if (i < 1024) b2[i] = (i < 256) ? bk2[i] : (i < 512 ? bq2[i - 256] : bv2[i - 512]);
}

template <bool HAS_BIAS>
__global__ __launch_bounds__(256) void gemv_nt(
    const float* __restrict__ a, const float* __restrict__ Bt, int ldb,
    const float* __restrict__ bias, float* __restrict__ out, int K)
{
    int w = threadIdx.x >> 6, lane = threadIdx.x & 63;
    int n = blockIdx.x * 4 + w;
    const float* row = Bt + (size_t)n * ldb;
    float s = 0.f;
    for (int k = lane; k < K; k += 64) s = fmaf(a[k], row[k], s);
#pragma unroll
    for (int o = 32; o; o >>= 1) s += __shfl_down(s, o);
    if (lane == 0) out[n] = HAS_BIAS ? s + bias[n] : s;
}

__global__ __launch_bounds__(256) void gemv_hl(
    const float* __restrict__ p, const unsigned short* __restrict__ Vh,
    const unsigned short* __restrict__ Vl, int ld, float* __restrict__ out, int K)
{
    int w = threadIdx.x >> 6, lane = threadIdx.x & 63;
    int d = blockIdx.x * 4 + w;
    const unsigned short* rh = Vh + (size_t)d * ld;
    const unsigned short* rl = Vl + (size_t)d * ld;
    float s = 0.f;
    for (int k = lane; k < K; k += 64) s = fmaf(p[k], bf2f(rh[k]) + bf2f(rl[k]), s);
#pragma unroll
    for (int o = 32; o; o >>= 1) s += __shfl_down(s, o);
    if (lane == 0) out[d] = s;
}

__global__ __launch_bounds__(256) void softmax_f32(float* __restrict__ S, int L)
{
    __shared__ float row[2048];
    __shared__ float red[8];
    const int tid = threadIdx.x;
    float* p = S + (size_t)blockIdx.x * L;
    float mx = -1e30f;
    for (int i = tid; i < L; i += 256) { float v = p[i]; row[i] = v; mx = fmaxf(mx, v); }
#pragma unroll
    for (int o = 32; o; o >>= 1) mx = fmaxf(mx, __shfl_down(mx, o));
    if ((tid & 63) == 0) red[tid >> 6] = mx;
    __syncthreads();
    mx = fmaxf(fmaxf(red[0], red[1]), fmaxf(red[2], red[3]));
    float sum = 0.f;
    for (int i = tid; i < L; i += 256) { float e = expf(row[i] - mx); row[i] = e; sum += e; }
#pragma unroll
    for (int o = 32; o; o >>= 1) sum += __shfl_down(sum, o);
    __syncthreads();
    if ((tid & 63) == 0) red[4 + (tid >> 6)] = sum;
    __syncthreads();
    float inv = 1.f / (red[4] + red[5] + red[6] + red[7]);
    for (int i = tid; i < L; i += 256) p[i] = row[i] * inv;
}

// ---------------------------------------------------------------------------
// Orchestration (batch 0 only; block-3 needs only the last query row).
// BIG region time-shared: proj partials -> flash Opart -> proj partials -> ...
// ---------------------------------------------------------------------------
extern "C" void kernel_launch(void* const* d_in, const int* in_sizes, int n_in,
                              void* d_out, int out_size, void* d_ws, size_t ws_size,
                              hipStream_t stream)
{
    const float* x   = (const float*)d_in[0];
    const float* Wk1 = (const float*)d_in[1];
    const float* bk1 = (const float*)d_in[2];
    const float* Wq1 = (const float*)d_in[3];
    const float* bq1 = (const float*)d_in[4];
    const float* Wk2 = (const float*)d_in[5];
    const float* bk2 = (const float*)d_in[6];
    const float* Wq2 = (const float*)d_in[7];
    const float* bq2 = (const float*)d_in[8];
    const float* Wv2 = (const float*)d_in[9];
    const float* bv2 = (const float*)d_in[10];
    float* out = (float*)d_out;

    const int S = 2048, D = 512;
    typedef unsigned short us;

    char* p = (char*)d_ws;
    float* C   = (float*)p;  p += (size_t)S * 1024 * 4;        // proj fp32 out (8.4 MB)
    float* BIG = (float*)p;  p += (size_t)8 * S * 512 * 4;     // partials / Opart (33.6 MB)
    float* Mp  = (float*)p;  p += (size_t)8 * S * 4;
    float* Lp  = (float*)p;  p += (size_t)8 * S * 4;
    us* Chh = (us*)p; p += (size_t)S * 1024 * 2;
    us* Cll = (us*)p; p += (size_t)S * 1024 * 2;
    us* Hh  = (us*)p; p += (size_t)S * D * 2;
    us* Hl  = (us*)p; p += (size_t)S * D * 2;
    us* xh  = (us*)p; p += (size_t)S * D * 2;
    us* xl  = (us*)p; p += (size_t)S * D * 2;
    us* VTh = (us*)p; p += (size_t)D * S * 2;
    us* VTl = (us*)p; p += (size_t)D * S * 2;
    us* WT1h = (us*)p; p += (size_t)512 * 512 * 2;
    us* WT1l = (us*)p; p += (size_t)512 * 512 * 2;
    us* WT2h = (us*)p; p += (size_t)1024 * 512 * 2;
    us* WT2l = (us*)p; p += (size_t)1024 * 512 * 2;
    float* b1 = (float*)p; p += 512 * 4;
    float* b2 = (float*)p; p += 1024 * 4;

    dim3 blk(256);
    const size_t PSTR  = (size_t)S * 512 / 4;
    const size_t PSTR2 = (size_t)S * 1024 / 4;

    // ---- setup ----
    convert_hl<<<dim3(S * D / 1024), blk, 0, stream>>>(x, xh, xl);
    tc_kernel<<<dim3(16, 64), blk, 0, stream>>>(x, 512, VTh, VTl, S, 0);     // x^T
    tc_kernel<<<dim3(8, 16), blk, 0, stream>>>(Wk1, 256, WT1h, WT1l, 512, 0);
    tc_kernel<<<dim3(8, 16), blk, 0, stream>>>(Wq1, 256, WT1h, WT1l, 512, 256);
    tc_kernel<<<dim3(8, 16), blk, 0, stream>>>(Wk2, 256, WT2h, WT2l, 512, 0);
    tc_kernel<<<dim3(8, 16), blk, 0, stream>>>(Wq2, 256, WT2h, WT2l, 512, 256);
    tc_kernel<<<dim3(16, 16), blk, 0, stream>>>(Wv2, 512, WT2h, WT2l, 512, 512);
    concat_bias<<<dim3(4), blk, 0, stream>>>(bk1, bq1, bk2, bq2, bv2, b1, b2);

    // ---- block 1: proj (K|Q fused) -> flash attention (v = x) ----
    gemm_bf16<512, 3><<<dim3(4, 16, 3), blk, 0, stream>>>(xh, xl, 512, WT1h, WT1l, 512, BIG, 512);
    reduce_kernel<3, true><<<dim3(S * 512 / 1024), blk, 0, stream>>>(BIG, PSTR, b1, C, Chh, Cll, 512);
    flash_attn<<<dim3(8, 32), blk, 0, stream>>>(Chh + 256, Cll + 256, Chh, Cll, 512,
                                                VTh, VTl, BIG, Mp, Lp);
    flash_combine<<<dim3(S), blk, 0, stream>>>(BIG, Mp, Lp, Hh, Hl);

    // ---- block 2: proj (K|Q|V fused), l2norm, V^T, flash ----
    gemm_bf16<512, 2><<<dim3(8, 16, 2), blk, 0, stream>>>(Hh, Hl, 512, WT2h, WT2l, 512, BIG, 1024);
    reduce_kernel<2, true><<<dim3(S * 1024 / 1024), blk, 0, stream>>>(BIG, PSTR2, b2, C, Chh, Cll, 1024);
    l2norm_kernel<<<dim3(S), blk, 0, stream>>>(C, 1024, 512, 512);
    tc_kernel<<<dim3(16, 64), blk, 0, stream>>>(C + 512, 1024, VTh, VTl, S, 0);
    flash_attn<<<dim3(8, 32), blk, 0, stream>>>(Chh + 256, Cll + 256, Chh, Cll, 1024,
                                                VTh, VTl, BIG, Mp, Lp);
    flash_combine<<<dim3(S), blk, 0, stream>>>(BIG, Mp, Lp, Hh, Hl);

    // ---- block 3: proj, l2norm, V^T, 1-row attention ----
    gemm_bf16<512, 2><<<dim3(8, 16, 2), blk, 0, stream>>>(Hh, Hl, 512, WT2h, WT2l, 512, BIG, 1024);
    reduce_kernel<2, true><<<dim3(S * 1024 / 1024), blk, 0, stream>>>(BIG, PSTR2, b2, C, Chh, Cll, 1024);
    l2norm_kernel<<<dim3(S), blk, 0, stream>>>(C, 1024, 512, 512);
    tc_kernel<<<dim3(16, 64), blk, 0, stream>>>(C + 512, 1024, VTh, VTl, S, 0);
    gemv_nt<false><<<dim3(S / 4), blk, 0, stream>>>(C + (size_t)(S - 1) * 1024 + 256, C, 1024,
                                                    nullptr, BIG, 256);
    softmax_f32<<<dim3(1), blk, 0, stream>>>(BIG, S);
    gemv_hl<<<dim3(D / 4), blk, 0, stream>>>(BIG, VTh, VTl, S, out, S);
}

// Round 5
// 389.528 us; speedup vs baseline: 1.2383x; 1.2383x over previous
//
#include <hip/hip_runtime.h>
#include <math.h>

typedef __attribute__((ext_vector_type(8))) short short8;
typedef __attribute__((ext_vector_type(4))) float f32x4;
typedef unsigned short us;

__device__ inline unsigned short f2bf_rn(float f) {
    unsigned u = __builtin_bit_cast(unsigned, f);
    u += 0x7FFF + ((u >> 16) & 1);
    return (unsigned short)(u >> 16);
}
__device__ inline float bf2f(unsigned short h) {
    unsigned u = ((unsigned)h) << 16;
    return __builtin_bit_cast(float, u);
}

// ---------------------------------------------------------------------------
// Pure-bf16 NT GEMM over virtual K' = 3*KSEG (Ah*Bh + Ah*Bl + Al*Bh, one fp32
// accumulator). 128x128 tile, BK=64, 4 waves. Reg-staged prefetch, raw
// s_barrier + lgkmcnt(0). LDS XOR swizzle slot^(row&7). NSPLIT over blockIdx.z.
// ---------------------------------------------------------------------------
#define ISSUE(ST, RA, RB)                                                      \
  do {                                                                         \
    int s_ = (ST);                                                             \
    int sg_ = s_ / SPS;                                                        \
    int k0_ = (s_ - sg_ * SPS) * 64;                                           \
    const unsigned short* Ap_ = (sg_ < 2) ? Ah : Al;                           \
    const unsigned short* Bp_ = (sg_ == 1) ? Bl : Bh;                          \
    _Pragma("unroll") for (int i_ = 0; i_ < 4; ++i_) {                         \
      RA[i_] = *(const uint4*)(Ap_ + (size_t)(bm + crow[i_]) * lda + k0_ + csl[i_] * 8); \
      RB[i_] = *(const uint4*)(Bp_ + (size_t)(bn + crow[i_]) * ldb + k0_ + csl[i_] * 8); \
    }                                                                          \
  } while (0)

#define PHASE(IT, RWa, RWb, RLa, RLb)                                          \
  do {                                                                         \
    _Pragma("unroll") for (int i_ = 0; i_ < 4; ++i_) {                         \
      int wsl_ = csl[i_] ^ (crow[i_] & 7);                                     \
      *(uint4*)&As[crow[i_]][wsl_ * 8] = RWa[i_];                              \
      *(uint4*)&Bs[crow[i_]][wsl_ * 8] = RWb[i_];                              \
    }                                                                          \
    if ((IT) + 1 < CHUNK) { ISSUE(st0 + (IT) + 1, RLa, RLb); }                 \
    asm volatile("s_waitcnt lgkmcnt(0)\n\ts_barrier" ::: "memory");            \
    _Pragma("unroll") for (int kk = 0; kk < 2; ++kk) {                         \
      short8 af[4], bf[4];                                                     \
      _Pragma("unroll") for (int f = 0; f < 4; ++f) {                          \
        int ar = wm * 64 + f * 16 + r15;                                       \
        int as_ = (kk * 4 + ksl) ^ (ar & 7);                                   \
        af[f] = *(const short8*)&As[ar][as_ * 8];                              \
        int br = wn * 64 + f * 16 + r15;                                       \
        int bs_ = (kk * 4 + ksl) ^ (br & 7);                                   \
        bf[f] = *(const short8*)&Bs[br][bs_ * 8];                              \
      }                                                                        \
      _Pragma("unroll") for (int i_ = 0; i_ < 4; ++i_)                         \
        _Pragma("unroll") for (int j_ = 0; j_ < 4; ++j_)                       \
          acc[i_][j_] = __builtin_amdgcn_mfma_f32_16x16x32_bf16(               \
              af[i_], bf[j_], acc[i_][j_], 0, 0, 0);                           \
    }                                                                          \
    asm volatile("s_barrier" ::: "memory");                                    \
  } while (0)

template <int KSEG, int NSPLIT>
__global__ __launch_bounds__(256, 2) void gemm_bf16(
    const unsigned short* __restrict__ Ah, const unsigned short* __restrict__ Al, int lda,
    const unsigned short* __restrict__ Bh, const unsigned short* __restrict__ Bl, int ldb,
    float* __restrict__ Cout, int ldc)
{
    constexpr int SPS = KSEG / 64;
    constexpr int NST = 3 * SPS;
    constexpr int CHUNK = NST / NSPLIT;

    __shared__ __align__(16) unsigned short As[128][64];
    __shared__ __align__(16) unsigned short Bs[128][64];

    const int tid = threadIdx.x, lane = tid & 63, w = tid >> 6;
    const int wm = w >> 1, wn = w & 1;
    const int bm = blockIdx.y * 128, bn = blockIdx.x * 128;
    const int st0 = blockIdx.z * CHUNK;
    const int r15 = lane & 15, ksl = lane >> 4;

    int crow[4], csl[4];
#pragma unroll
    for (int i = 0; i < 4; ++i) { int c = tid + i * 256; crow[i] = c >> 3; csl[i] = c & 7; }

    f32x4 acc[4][4];
#pragma unroll
    for (int i = 0; i < 4; ++i)
#pragma unroll
        for (int j = 0; j < 4; ++j) acc[i][j] = (f32x4){0.f, 0.f, 0.f, 0.f};

    uint4 rA0[4], rB0[4], rA1[4], rB1[4];
    ISSUE(st0, rA0, rB0);

#pragma unroll 1
    for (int it = 0; it < CHUNK; it += 2) {
        PHASE(it,     rA0, rB0, rA1, rB1);
        PHASE(it + 1, rA1, rB1, rA0, rB0);
    }

    float* Cz = Cout + (size_t)blockIdx.z * (size_t)(gridDim.y * 128) * ldc;
#pragma unroll
    for (int i = 0; i < 4; ++i) {
        int rowb = bm + wm * 64 + i * 16 + (lane >> 4) * 4;
#pragma unroll
        for (int j = 0; j < 4; ++j) {
            int colb = bn + wn * 64 + j * 16 + r15;
#pragma unroll
            for (int r = 0; r < 4; ++r)
                Cz[(size_t)(rowb + r) * ldc + colb] = acc[i][j][r];
        }
    }
}

// ---------------------------------------------------------------------------
// Reduce NS partials + bias -> C fp32 and hi/lo bf16.
// L2N: block == one 1024-wide row; threads 128..255 hold V half (cols 512+),
// fuse the row L2-normalize of that half (replaces l2norm kernel + pass).
// ---------------------------------------------------------------------------
template <int NS, bool BIAS, bool L2N>
__global__ __launch_bounds__(256) void reduce_kernel(
    const float* __restrict__ part, size_t pstride4,
    const float* __restrict__ bias, float* __restrict__ C,
    unsigned short* __restrict__ Ch, unsigned short* __restrict__ Cl, int N)
{
    __shared__ float red[4];
    const int tid = threadIdx.x;
    size_t idx = (size_t)blockIdx.x * 256 + tid;
    const float4* p = (const float4*)part;
    float4 s = p[idx];
#pragma unroll
    for (int z = 1; z < NS; ++z) {
        float4 t = p[idx + (size_t)z * pstride4];
        s.x += t.x; s.y += t.y; s.z += t.z; s.w += t.w;
    }
    if (BIAS) {
        int col = (int)((idx * 4) & (size_t)(N - 1));
        s.x += bias[col]; s.y += bias[col + 1]; s.z += bias[col + 2]; s.w += bias[col + 3];
    }
    if (L2N) {
        // threads 128..255 (waves 2,3) own cols 512..1023 of this row
        float ss = (tid >= 128) ? (s.x * s.x + s.y * s.y + s.z * s.z + s.w * s.w) : 0.f;
#pragma unroll
        for (int o = 32; o; o >>= 1) ss += __shfl_down(ss, o);
        if ((tid & 63) == 0) red[tid >> 6] = ss;
        __syncthreads();
        if (tid >= 128) {
            float scale = 1.f / sqrtf(red[2] + red[3]);
            s.x *= scale; s.y *= scale; s.z *= scale; s.w *= scale;
        }
    }
    ((float4*)C)[idx] = s;
    float v[4] = {s.x, s.y, s.z, s.w};
    unsigned short h[4], l[4];
#pragma unroll
    for (int q = 0; q < 4; ++q) { h[q] = f2bf_rn(v[q]); l[q] = f2bf_rn(v[q] - bf2f(h[q])); }
    uint2 hp = make_uint2((unsigned)h[0] | ((unsigned)h[1] << 16), (unsigned)h[2] | ((unsigned)h[3] << 16));
    uint2 lp = make_uint2((unsigned)l[0] | ((unsigned)l[1] << 16), (unsigned)l[2] | ((unsigned)l[3] << 16));
    ((uint2*)Ch)[idx] = hp;
    ((uint2*)Cl)[idx] = lp;
}

// ---------------------------------------------------------------------------
// Flash attention, split-bf16, online softmax with defer-max (thr=8).
// grid (z=8 kv-splits, 32 q-tiles, 2 d-chunks) = 512 blocks -> 2 blocks/CU.
// 4 waves x 16 q-rows; wave w owns d = dblk*256 + w*64 .. +64 (4 dt).
// QK^T recomputed per d-chunk (cheap); K in swizzled LDS; P via LDS;
// V B-frags direct from global. Partials Opart[z][2048][512] fp32 + M/L.
// ---------------------------------------------------------------------------
#define SLK(r, s) ((s) ^ (((s) >> 3) & 3) ^ ((((r) ^ ((r) >> 3))) & 7))

__global__ __launch_bounds__(256, 2) void flash_attn(
    const unsigned short* __restrict__ Qh, const unsigned short* __restrict__ Ql,
    const unsigned short* __restrict__ Kh, const unsigned short* __restrict__ Kl,
    int ldqk,
    const unsigned short* __restrict__ VTh, const unsigned short* __restrict__ VTl,
    float* __restrict__ Opart, float* __restrict__ Mpart, float* __restrict__ Lpart)
{
    const int tid = threadIdx.x, lane = tid & 63, w = tid >> 6;
    const int z = blockIdx.x;          // kv split
    const int q0 = blockIdx.y * 64;
    const int dblk = blockIdx.z;       // d-chunk 0/1 (256 each)
    const int s0 = z * 256;
    const int cc = lane & 15, g = lane >> 4;
    const int dbase = dblk * 256 + w * 64;

    __shared__ __align__(16) unsigned short KsH[32][256], KsL[32][256];
    __shared__ __align__(16) unsigned short PsH[64][32], PsL[64][32];
    __shared__ float Fs[64];
    __shared__ int flagAny[4];

    // Q fragments (wave's 16 q-rows, hi+lo)
    short8 qh[8], qlv[8];
#pragma unroll
    for (int ks = 0; ks < 8; ++ks) {
        const size_t qoff = (size_t)(q0 + w * 16 + cc) * ldqk + ks * 32 + g * 8;
        qh[ks]  = *(const short8*)(Qh + qoff);
        qlv[ks] = *(const short8*)(Ql + qoff);
    }

    f32x4 acc[4][4];
#pragma unroll
    for (int a = 0; a < 4; ++a)
#pragma unroll
        for (int b = 0; b < 4; ++b) acc[a][b] = (f32x4){0.f, 0.f, 0.f, 0.f};
    float m[4] = {-1e30f, -1e30f, -1e30f, -1e30f};
    float l[4] = {0.f, 0.f, 0.f, 0.f};

#pragma unroll 1
    for (int sub = 0; sub < 8; ++sub) {
        __syncthreads();   // previous subtile's Ks/Ps/Fs reads done
        // ---- stage K subtile (32 kv x 256 k, hi+lo) into swizzled LDS ----
#pragma unroll
        for (int i = 0; i < 4; ++i) {
            int idx = tid + i * 256;                 // 0..1023
            int row = (idx >> 3) & 31;
            int sl  = (idx & 7) | ((idx >> 8) << 3); // 16B slot 0..31
            size_t go = (size_t)(s0 + sub * 32 + row) * ldqk + sl * 8;
            uint4 vh = *(const uint4*)(Kh + go);
            uint4 vl = *(const uint4*)(Kl + go);
            int sw = SLK(row, sl);
            *(uint4*)&KsH[row][sw * 8] = vh;
            *(uint4*)&KsL[row][sw * 8] = vl;
        }
        __syncthreads();

        // ---- QK^T: S[16 q][32 kv], 3-pass split ----
        f32x4 sac[2];
        sac[0] = (f32x4){0.f, 0.f, 0.f, 0.f};
        sac[1] = (f32x4){0.f, 0.f, 0.f, 0.f};
#pragma unroll
        for (int ks = 0; ks < 8; ++ks) {
#pragma unroll
            for (int t = 0; t < 2; ++t) {
                int row = t * 16 + cc;
                int sw = SLK(row, ks * 4 + g);
                short8 bh = *(const short8*)&KsH[row][sw * 8];
                short8 bl = *(const short8*)&KsL[row][sw * 8];
                sac[t] = __builtin_amdgcn_mfma_f32_16x16x32_bf16(qh[ks], bh, sac[t], 0, 0, 0);
                sac[t] = __builtin_amdgcn_mfma_f32_16x16x32_bf16(qh[ks], bl, sac[t], 0, 0, 0);
                sac[t] = __builtin_amdgcn_mfma_f32_16x16x32_bf16(qlv[ks], bh, sac[t], 0, 0, 0);
            }
        }

        // ---- online softmax (rows r -> q = w*16 + g*4 + r) ----
        float mt[4], fr[4];
        bool nb = false;
#pragma unroll
        for (int r = 0; r < 4; ++r) {
            float v = fmaxf(sac[0][r], sac[1][r]);
#pragma unroll
            for (int o = 8; o >= 1; o >>= 1) v = fmaxf(v, __shfl_xor(v, o));
            mt[r] = v;
            nb = nb || (v > m[r] + 8.f);
        }
        const int need = __any((int)nb);
        if (need) {
#pragma unroll
            for (int r = 0; r < 4; ++r) {
                float mn = fmaxf(m[r], mt[r]);
                fr[r] = __expf(m[r] - mn);
                m[r] = mn;
                l[r] *= fr[r];
            }
        } else {
#pragma unroll
            for (int r = 0; r < 4; ++r) fr[r] = 1.f;
        }
        if (cc == 0) {
#pragma unroll
            for (int r = 0; r < 4; ++r) Fs[w * 16 + g * 4 + r] = fr[r];
        }
        if (lane == 0) flagAny[w] = need;

        // ---- P = exp(S - m): accumulate l, hi/lo to swizzled LDS ----
#pragma unroll
        for (int t = 0; t < 2; ++t) {
            float ps[4];
#pragma unroll
            for (int r = 0; r < 4; ++r) {
                float pv = __expf(sac[t][r] - m[r]);
                ps[r] = pv;
                unsigned short ph = f2bf_rn(pv);
                unsigned short pl = f2bf_rn(pv - bf2f(ph));
                int qq = w * 16 + g * 4 + r;
                int kv = cc + 16 * t;
                int col = (((kv >> 3) ^ (qq & 3)) << 3) | (kv & 7);
                PsH[qq][col] = ph;
                PsL[qq][col] = pl;
            }
#pragma unroll
            for (int r = 0; r < 4; ++r) {
                float sv = ps[r];
#pragma unroll
                for (int o = 8; o >= 1; o >>= 1) sv += __shfl_xor(sv, o);
                l[r] += sv;
            }
        }
        __syncthreads();   // P, Fs, flags visible block-wide

        // ---- rescale acc if any wave's max moved ----
        int anyf = flagAny[0] | flagAny[1] | flagAny[2] | flagAny[3];
        if (anyf) {
#pragma unroll
            for (int qt = 0; qt < 4; ++qt)
#pragma unroll
                for (int r = 0; r < 4; ++r) {
                    float fq = Fs[qt * 16 + g * 4 + r];
#pragma unroll
                    for (int dt = 0; dt < 4; ++dt) acc[qt][dt][r] *= fq;
                }
        }

        // ---- PV: acc[qt][dt] += P * V  (V B-frags direct from global) ----
        short8 pah[4], pal[4];
#pragma unroll
        for (int qt = 0; qt < 4; ++qt) {
            int qr = qt * 16 + cc;
            int col = (g ^ (qr & 3)) << 3;
            pah[qt] = *(const short8*)&PsH[qr][col];
            pal[qt] = *(const short8*)&PsL[qr][col];
        }
#pragma unroll
        for (int dt = 0; dt < 4; ++dt) {
            size_t vo = (size_t)(dbase + dt * 16 + cc) * 2048 + s0 + sub * 32 + g * 8;
            short8 vh = *(const short8*)(VTh + vo);
            short8 vl = *(const short8*)(VTl + vo);
#pragma unroll
            for (int qt = 0; qt < 4; ++qt) {
                acc[qt][dt] = __builtin_amdgcn_mfma_f32_16x16x32_bf16(pah[qt], vh, acc[qt][dt], 0, 0, 0);
                acc[qt][dt] = __builtin_amdgcn_mfma_f32_16x16x32_bf16(pah[qt], vl, acc[qt][dt], 0, 0, 0);
                acc[qt][dt] = __builtin_amdgcn_mfma_f32_16x16x32_bf16(pal[qt], vh, acc[qt][dt], 0, 0, 0);
            }
        }
    }

    // ---- epilogue: partial O + softmax stats ----
#pragma unroll
    for (int qt = 0; qt < 4; ++qt)
#pragma unroll
        for (int dt = 0; dt < 4; ++dt)
#pragma unroll
            for (int r = 0; r < 4; ++r) {
                int row = q0 + qt * 16 + g * 4 + r;
                int col = dbase + dt * 16 + cc;
                Opart[((size_t)z * 2048 + row) * 512 + col] = acc[qt][dt][r];
            }
    if (dblk == 0 && cc == 0) {
#pragma unroll
        for (int r = 0; r < 4; ++r) {
            int row = q0 + w * 16 + g * 4 + r;
            Mpart[z * 2048 + row] = m[r];
            Lpart[z * 2048 + row] = l[r];
        }
    }
}

// ---------------------------------------------------------------------------
// Combine 8 kv-split partials -> O row, write hi/lo bf16. One block per q-row.
// ---------------------------------------------------------------------------
__global__ __launch_bounds__(256) void flash_combine(
    const float* __restrict__ Opart, const float* __restrict__ Mpart,
    const float* __restrict__ Lpart,
    unsigned short* __restrict__ Oh, unsigned short* __restrict__ Ol)
{
    const int q = blockIdx.x;
    const int tid = threadIdx.x;
    float wz[8];
    float mstar = -1e30f;
#pragma unroll
    for (int zz = 0; zz < 8; ++zz) { wz[zz] = Mpart[zz * 2048 + q]; mstar = fmaxf(mstar, wz[zz]); }
    float L = 0.f;
#pragma unroll
    for (int zz = 0; zz < 8; ++zz) {
        float e = __expf(wz[zz] - mstar);
        L += e * Lpart[zz * 2048 + q];
        wz[zz] = e;
    }
    float invL = 1.f / L;
    int d = tid * 2;
    float sx = 0.f, sy = 0.f;
#pragma unroll
    for (int zz = 0; zz < 8; ++zz) {
        const float2 t = *(const float2*)(Opart + ((size_t)zz * 2048 + q) * 512 + d);
        sx += wz[zz] * t.x;
        sy += wz[zz] * t.y;
    }
    sx *= invL; sy *= invL;
    unsigned short h0 = f2bf_rn(sx), h1 = f2bf_rn(sy);
    unsigned short l0 = f2bf_rn(sx - bf2f(h0)), l1 = f2bf_rn(sy - bf2f(h1));
    *(unsigned*)(Oh + (size_t)q * 512 + d) = (unsigned)h0 | ((unsigned)h1 << 16);
    *(unsigned*)(Ol + (size_t)q * 512 + d) = (unsigned)l0 | ((unsigned)l1 << 16);
}

// ---------------------------------------------------------------------------
// Transpose-convert fp32 -> hi/lo bf16 transposed.
// ---------------------------------------------------------------------------
__global__ __launch_bounds__(256) void tc_kernel(
    const float* __restrict__ in, int ldin,
    unsigned short* __restrict__ oh, unsigned short* __restrict__ ol,
    int ldo, int rowoff)
{
    __shared__ float tile[32][33];
    int bx = blockIdx.x * 32, by = blockIdx.y * 32;
    int tx = threadIdx.x & 31, ty = threadIdx.x >> 5;
#pragma unroll
    for (int i = 0; i < 32; i += 8)
        tile[ty + i][tx] = in[(size_t)(by + ty + i) * ldin + bx + tx];
    __syncthreads();
#pragma unroll
    for (int i = 0; i < 32; i += 8) {
        float v = tile[tx][ty + i];
        unsigned short h = f2bf_rn(v);
        unsigned short l = f2bf_rn(v - bf2f(h));
        size_t o = (size_t)(rowoff + bx + ty + i) * ldo + by + tx;
        oh[o] = h; ol[o] = l;
    }
}

// ---------------------------------------------------------------------------
// Elementwise fp32 -> hi/lo bf16.
// ---------------------------------------------------------------------------
__global__ __launch_bounds__(256) void convert_hl(
    const float* __restrict__ in, unsigned short* __restrict__ oh,
    unsigned short* __restrict__ ol)
{
    size_t idx = (size_t)blockIdx.x * 256 + threadIdx.x;
    float4 s = ((const float4*)in)[idx];
    float v[4] = {s.x, s.y, s.z, s.w};
    unsigned short h[4], l[4];
#pragma unroll
    for (int q = 0; q < 4; ++q) { h[q] = f2bf_rn(v[q]); l[q] = f2bf_rn(v[q] - bf2f(h[q])); }
    uint2 hp = make_uint2((unsigned)h[0] | ((unsigned)h[1] << 16), (unsigned)h[2] | ((unsigned)h[3] << 16));
    uint2 lp = make_uint2((unsigned)l[0] | ((unsigned)l[1] << 16), (unsigned)l[2] | ((unsigned)l[3] << 16));
    ((uint2*)oh)[idx] = hp;
    ((uint2*)ol)[idx] = lp;
}

__global__ __launch_bounds__(256) void concat_bias(
    const float* bk1, const float* bq1, const float* bk2, const float* bq2,
    const float* bv2, float* b1, float* b2)
{
    int i = blockIdx.x * 256 + threadIdx.x;
    if (i < 512) b1[i] = (i < 256) ? bk1[i] : bq1[i - 256];
    if (i < 1024) b2[i] = (i < 256) ? bk2[i] : (i < 512 ? bq2[i - 256] : bv2[i - 512]);
}

template <bool HAS_BIAS>
__global__ __launch_bounds__(256) void gemv_nt(
    const float* __restrict__ a, const float* __restrict__ Bt, int ldb,
    const float* __restrict__ bias, float* __restrict__ out, int K)
{
    int w = threadIdx.x >> 6, lane = threadIdx.x & 63;
    int n = blockIdx.x * 4 + w;
    const float* row = Bt + (size_t)n * ldb;
    float s = 0.f;
    for (int k = lane; k < K; k += 64) s = fmaf(a[k], row[k], s);
#pragma unroll
    for (int o = 32; o; o >>= 1) s += __shfl_down(s, o);
    if (lane == 0) out[n] = HAS_BIAS ? s + bias[n] : s;
}

__global__ __launch_bounds__(256) void gemv_hl(
    const float* __restrict__ p, const unsigned short* __restrict__ Vh,
    const unsigned short* __restrict__ Vl, int ld, float* __restrict__ out, int K)
{
    int w = threadIdx.x >> 6, lane = threadIdx.x & 63;
    int d = blockIdx.x * 4 + w;
    const unsigned short* rh = Vh + (size_t)d * ld;
    const unsigned short* rl = Vl + (size_t)d * ld;
    float s = 0.f;
    for (int k = lane; k < K; k += 64) s = fmaf(p[k], bf2f(rh[k]) + bf2f(rl[k]), s);
#pragma unroll
    for (int o = 32; o; o >>= 1) s += __shfl_down(s, o);
    if (lane == 0) out[d] = s;
}

__global__ __launch_bounds__(256) void softmax_f32(float* __restrict__ S, int L)
{
    __shared__ float row[2048];
    __shared__ float red[8];
    const int tid = threadIdx.x;
    float* p = S + (size_t)blockIdx.x * L;
    float mx = -1e30f;
    for (int i = tid; i < L; i += 256) { float v = p[i]; row[i] = v; mx = fmaxf(mx, v); }
#pragma unroll
    for (int o = 32; o; o >>= 1) mx = fmaxf(mx, __shfl_down(mx, o));
    if ((tid & 63) == 0) red[tid >> 6] = mx;
    __syncthreads();
    mx = fmaxf(fmaxf(red[0], red[1]), fmaxf(red[2], red[3]));
    float sum = 0.f;
    for (int i = tid; i < L; i += 256) { float e = expf(row[i] - mx); row[i] = e; sum += e; }
#pragma unroll
    for (int o = 32; o; o >>= 1) sum += __shfl_down(sum, o);
    __syncthreads();
    if ((tid & 63) == 0) red[4 + (tid >> 6)] = sum;
    __syncthreads();
    float inv = 1.f / (red[4] + red[5] + red[6] + red[7]);
    for (int i = tid; i < L; i += 256) p[i] = row[i] * inv;
}

// ---------------------------------------------------------------------------
// Orchestration (batch 0 only; block-3 needs only the last query row).
// ---------------------------------------------------------------------------
extern "C" void kernel_launch(void* const* d_in, const int* in_sizes, int n_in,
                              void* d_out, int out_size, void* d_ws, size_t ws_size,
                              hipStream_t stream)
{
    const float* x   = (const float*)d_in[0];
    const float* Wk1 = (const float*)d_in[1];
    const float* bk1 = (const float*)d_in[2];
    const float* Wq1 = (const float*)d_in[3];
    const float* bq1 = (const float*)d_in[4];
    const float* Wk2 = (const float*)d_in[5];
    const float* bk2 = (const float*)d_in[6];
    const float* Wq2 = (const float*)d_in[7];
    const float* bq2 = (const float*)d_in[8];
    const float* Wv2 = (const float*)d_in[9];
    const float* bv2 = (const float*)d_in[10];
    float* out = (float*)d_out;

    const int S = 2048, D = 512;

    char* p = (char*)d_ws;
    float* C   = (float*)p;  p += (size_t)S * 1024 * 4;        // proj fp32 out (8.4 MB)
    float* BIG = (float*)p;  p += (size_t)8 * S * 512 * 4;     // partials / Opart (33.6 MB)
    float* Mp  = (float*)p;  p += (size_t)8 * S * 4;
    float* Lp  = (float*)p;  p += (size_t)8 * S * 4;
    us* Chh = (us*)p; p += (size_t)S * 1024 * 2;
    us* Cll = (us*)p; p += (size_t)S * 1024 * 2;
    us* Hh  = (us*)p; p += (size_t)S * D * 2;
    us* Hl  = (us*)p; p += (size_t)S * D * 2;
    us* xh  = (us*)p; p += (size_t)S * D * 2;
    us* xl  = (us*)p; p += (size_t)S * D * 2;
    us* VTh = (us*)p; p += (size_t)D * S * 2;
    us* VTl = (us*)p; p += (size_t)D * S * 2;
    us* WT1h = (us*)p; p += (size_t)512 * 512 * 2;
    us* WT1l = (us*)p; p += (size_t)512 * 512 * 2;
    us* WT2h = (us*)p; p += (size_t)1024 * 512 * 2;
    us* WT2l = (us*)p; p += (size_t)1024 * 512 * 2;
    float* b1 = (float*)p; p += 512 * 4;
    float* b2 = (float*)p; p += 1024 * 4;

    dim3 blk(256);
    const size_t PSTR  = (size_t)S * 512 / 4;    // z-stride of 512-wide partials (float4)
    const size_t PSTR2 = (size_t)S * 1024 / 4;   // 1024-wide

    // ---- setup ----
    convert_hl<<<dim3(S * D / 1024), blk, 0, stream>>>(x, xh, xl);
    tc_kernel<<<dim3(16, 64), blk, 0, stream>>>(x, 512, VTh, VTl, S, 0);     // x^T
    tc_kernel<<<dim3(8, 16), blk, 0, stream>>>(Wk1, 256, WT1h, WT1l, 512, 0);
    tc_kernel<<<dim3(8, 16), blk, 0, stream>>>(Wq1, 256, WT1h, WT1l, 512, 256);
    tc_kernel<<<dim3(8, 16), blk, 0, stream>>>(Wk2, 256, WT2h, WT2l, 512, 0);
    tc_kernel<<<dim3(8, 16), blk, 0, stream>>>(Wq2, 256, WT2h, WT2l, 512, 256);
    tc_kernel<<<dim3(16, 16), blk, 0, stream>>>(Wv2, 512, WT2h, WT2l, 512, 512);
    concat_bias<<<dim3(4), blk, 0, stream>>>(bk1, bq1, bk2, bq2, bv2, b1, b2);

    // ---- block 1: proj (K|Q fused, z=6 -> 384 blocks) -> flash (v = x) ----
    gemm_bf16<512, 6><<<dim3(4, 16, 6), blk, 0, stream>>>(xh, xl, 512, WT1h, WT1l, 512, BIG, 512);
    reduce_kernel<6, true, false><<<dim3(S * 512 / 1024), blk, 0, stream>>>(BIG, PSTR, b1, C, Chh, Cll, 512);
    flash_attn<<<dim3(8, 32, 2), blk, 0, stream>>>(Chh + 256, Cll + 256, Chh, Cll, 512,
                                                   VTh, VTl, BIG, Mp, Lp);
    flash_combine<<<dim3(S), blk, 0, stream>>>(BIG, Mp, Lp, Hh, Hl);

    // ---- block 2: proj (K|Q|V fused, z=4 -> 512 blocks) + fused l2norm, V^T, flash ----
    gemm_bf16<512, 4><<<dim3(8, 16, 4), blk, 0, stream>>>(Hh, Hl, 512, WT2h, WT2l, 512, BIG, 1024);
    reduce_kernel<4, true, true><<<dim3(S * 1024 / 1024), blk, 0, stream>>>(BIG, PSTR2, b2, C, Chh, Cll, 1024);
    tc_kernel<<<dim3(16, 64), blk, 0, stream>>>(C + 512, 1024, VTh, VTl, S, 0);
    flash_attn<<<dim3(8, 32, 2), blk, 0, stream>>>(Chh + 256, Cll + 256, Chh, Cll, 1024,
                                                   VTh, VTl, BIG, Mp, Lp);
    flash_combine<<<dim3(S), blk, 0, stream>>>(BIG, Mp, Lp, Hh, Hl);

    // ---- block 3: proj + fused l2norm, V^T, 1-row attention ----
    gemm_bf16<512, 4><<<dim3(8, 16, 4), blk, 0, stream>>>(Hh, Hl, 512, WT2h, WT2l, 512, BIG, 1024);
    reduce_kernel<4, true, true><<<dim3(S * 1024 / 1024), blk, 0, stream>>>(BIG, PSTR2, b2, C, Chh, Cll, 1024);
    tc_kernel<<<dim3(16, 64), blk, 0, stream>>>(C + 512, 1024, VTh, VTl, S, 0);
    gemv_nt<false><<<dim3(S / 4), blk, 0, stream>>>(C + (size_t)(S - 1) * 1024 + 256, C, 1024,
                                                    nullptr, BIG, 256);
    softmax_f32<<<dim3(1), blk, 0, stream>>>(BIG, S);
    gemv_hl<<<dim3(D / 4), blk, 0, stream>>>(BIG, VTh, VTl, S, out, S);
}